// Round 1
// baseline (928.978 us; speedup 1.0000x reference)
//
#include <hip/hip_runtime.h>
#include <math.h>

#define NB    16      // batch
#define CDIM  256
#define COUT  144     // 64 q + 16 k + 64 v
#define MPIX  4096    // 64*64
#define DIMK  16
#define NHEADS 4
#define DIMV  64
#define SCOPE 23
#define PADH  11
#define BNEPS 1e-5f

// ---------------- K1: qkv = w_qkv @ x  (per batch: 144x256 @ 256x4096) ----------------
// grid (16 mtiles, 3 otiles, 16 b), block 256
__global__ void __launch_bounds__(256) gemm_qkv(const float* __restrict__ x,
                                                const float* __restrict__ w,
                                                float* __restrict__ qkv) {
    __shared__ float xs[32][256];
    __shared__ float wsb[48][33];
    int mt = blockIdx.x, ot = blockIdx.y, b = blockIdx.z;
    int m0 = mt * 256, o0 = ot * 48;
    int tid = threadIdx.x;
    int to = tid >> 6;   // 0..3
    int tm = tid & 63;   // 0..63
    float acc[12][4];
#pragma unroll
    for (int i = 0; i < 12; i++)
#pragma unroll
        for (int j = 0; j < 4; j++) acc[i][j] = 0.f;

    const float* xb = x + (size_t)b * CDIM * MPIX;
    for (int k0 = 0; k0 < CDIM; k0 += 32) {
        __syncthreads();
        // load x chunk 32 x 256 (coalesced rows)
#pragma unroll
        for (int i = 0; i < 32; i++)
            xs[i][tid] = xb[(size_t)(k0 + i) * MPIX + m0 + tid];
        // load w chunk 48 x 32
#pragma unroll
        for (int i = 0; i < 6; i++) {
            int idx = i * 256 + tid;
            int o = idx >> 5, r = idx & 31;
            wsb[o][r] = w[(size_t)(o0 + o) * CDIM + k0 + r];
        }
        __syncthreads();
#pragma unroll 4
        for (int r = 0; r < 32; r++) {
            float4 xv = *(const float4*)&xs[r][tm * 4];
#pragma unroll
            for (int i = 0; i < 12; i++) {
                float wv = wsb[to * 12 + i][r];
                acc[i][0] = fmaf(wv, xv.x, acc[i][0]);
                acc[i][1] = fmaf(wv, xv.y, acc[i][1]);
                acc[i][2] = fmaf(wv, xv.z, acc[i][2]);
                acc[i][3] = fmaf(wv, xv.w, acc[i][3]);
            }
        }
    }
#pragma unroll
    for (int i = 0; i < 12; i++) {
        float4 v = make_float4(acc[i][0], acc[i][1], acc[i][2], acc[i][3]);
        *(float4*)&qkv[((size_t)b * COUT + o0 + to * 12 + i) * MPIX + m0 + tm * 4] = v;
    }
}

// ---------------- K2: BN partial sums per (channel, batch) ----------------
// stat channels: 0..63 -> q channel c (o=c); 64..127 -> v channel (o=80+c-64)
// grid (128, 16), block 256
__global__ void stats_partial(const float* __restrict__ qkv, float* __restrict__ part) {
    int ch = blockIdx.x, b = blockIdx.y;
    int o = (ch < 64) ? ch : (80 + ch - 64);
    const float* row = qkv + ((size_t)b * COUT + o) * MPIX;
    int tid = threadIdx.x;
    float s = 0.f, s2 = 0.f;
    for (int i = tid; i < MPIX; i += 256) {
        float v = row[i];
        s += v;
        s2 = fmaf(v, v, s2);
    }
#pragma unroll
    for (int off = 32; off > 0; off >>= 1) {
        s += __shfl_down(s, off);
        s2 += __shfl_down(s2, off);
    }
    __shared__ float red[8];
    int wid = tid >> 6, lane = tid & 63;
    if (lane == 0) { red[wid * 2] = s; red[wid * 2 + 1] = s2; }
    __syncthreads();
    if (tid == 0) {
        float ts = 0.f, ts2 = 0.f;
#pragma unroll
        for (int w2 = 0; w2 < 4; w2++) { ts += red[w2 * 2]; ts2 += red[w2 * 2 + 1]; }
        part[(size_t)(ch * 16 + b) * 2 + 0] = ts;
        part[(size_t)(ch * 16 + b) * 2 + 1] = ts2;
    }
}

// ---------------- K3: finalize scale/shift ----------------
// 1 block, 128 threads
__global__ void stats_finalize(const float* __restrict__ part,
                               const float* __restrict__ gq, const float* __restrict__ bq,
                               const float* __restrict__ gv, const float* __restrict__ bv,
                               float* __restrict__ ascale, float* __restrict__ dshift) {
    int ch = threadIdx.x;
    if (ch >= 128) return;
    float s = 0.f, s2 = 0.f;
    for (int b = 0; b < 16; b++) {
        s += part[(size_t)(ch * 16 + b) * 2 + 0];
        s2 += part[(size_t)(ch * 16 + b) * 2 + 1];
    }
    const float invN = 1.0f / 65536.0f;
    float mean = s * invN;
    float var = s2 * invN - mean * mean;
    float g = (ch < 64) ? gq[ch] : gv[ch - 64];
    float be = (ch < 64) ? bq[ch] : bv[ch - 64];
    float a = g * rsqrtf(var + BNEPS);
    ascale[ch] = a;
    dshift[ch] = be - mean * a;
}

// ---------------- K4: softmax over m for each (b, kc) ----------------
// grid 256, block 256
__global__ void softmax_k(const float* __restrict__ qkv, float* __restrict__ p) {
    int bk = blockIdx.x;
    int b = bk >> 4, kc = bk & 15;
    const float* row = qkv + ((size_t)b * COUT + 64 + kc) * MPIX;
    int tid = threadIdx.x;
    float v[16];
    float mx = -INFINITY;
#pragma unroll
    for (int i = 0; i < 16; i++) {
        v[i] = row[tid + i * 256];
        mx = fmaxf(mx, v[i]);
    }
#pragma unroll
    for (int off = 32; off > 0; off >>= 1) mx = fmaxf(mx, __shfl_down(mx, off));
    __shared__ float redm[4];
    __shared__ float bm;
    int wid = tid >> 6, lane = tid & 63;
    if (lane == 0) redm[wid] = mx;
    __syncthreads();
    if (tid == 0) bm = fmaxf(fmaxf(redm[0], redm[1]), fmaxf(redm[2], redm[3]));
    __syncthreads();
    mx = bm;
    float s = 0.f;
#pragma unroll
    for (int i = 0; i < 16; i++) {
        v[i] = expf(v[i] - mx);
        s += v[i];
    }
#pragma unroll
    for (int off = 32; off > 0; off >>= 1) s += __shfl_down(s, off);
    __shared__ float reds[4];
    __shared__ float bs;
    if (lane == 0) reds[wid] = s;
    __syncthreads();
    if (tid == 0) bs = reds[0] + reds[1] + reds[2] + reds[3];
    __syncthreads();
    float r = 1.0f / bs;
    float* prow = p + ((size_t)b * 16 + kc) * MPIX;
#pragma unroll
    for (int i = 0; i < 16; i++) prow[tid + i * 256] = v[i] * r;
}

// ---------------- K5: content lambda partials ----------------
// cl[b,k,v] = sum_m p[b,k,m] * v_bn[b,v,m] ; partial over m-chunks of 256
// grid (16 mchunks, 16 b), block 256
__global__ void cl_partial(const float* __restrict__ qkv, const float* __restrict__ p,
                           const float* __restrict__ ascale, const float* __restrict__ dshift,
                           float* __restrict__ clpart) {
    __shared__ float vsT[128][65];
    int mc = blockIdx.x, b = blockIdx.y;
    int m0 = mc * 256;
    int tid = threadIdx.x;
    int vc = tid & 63, kg = tid >> 6;
    float acc[4] = {0.f, 0.f, 0.f, 0.f};
    for (int half = 0; half < 2; half++) {
        int mh = m0 + half * 128;
        __syncthreads();
        for (int i = tid; i < 64 * 128; i += 256) {
            int r = i >> 7, c = i & 127;
            vsT[c][r] = fmaf(ascale[64 + r], qkv[((size_t)b * COUT + 80 + r) * MPIX + mh + c],
                             dshift[64 + r]);
        }
        __syncthreads();
        for (int mm = 0; mm < 128; mm++) {
            float vv = vsT[mm][vc];
#pragma unroll
            for (int i = 0; i < 4; i++) {
                int kc = kg * 4 + i;
                acc[i] = fmaf(p[((size_t)b * 16 + kc) * MPIX + mh + mm], vv, acc[i]);
            }
        }
    }
#pragma unroll
    for (int i = 0; i < 4; i++) {
        int kc = kg * 4 + i;
        clpart[(((size_t)b * 16 + mc) * 16 + kc) * 64 + vc] = acc[i];
    }
}

// grid 16 (b), block 256
__global__ void cl_reduce(const float* __restrict__ clpart, float* __restrict__ cl) {
    int b = blockIdx.x;
    for (int o = threadIdx.x; o < 1024; o += 256) {
        float s = 0.f;
        for (int mc = 0; mc < 16; mc++)
            s += clpart[((size_t)b * 16 + mc) * 1024 + o];
        cl[(size_t)b * 1024 + o] = s;
    }
}

// ---------------- K7: fused 23x23 conv + lambda epilogue ----------------
// grid (64 vc, 16 b), block 256
#define SVW 88  // padded-image row stride
__global__ void __launch_bounds__(256) lambda_main(
    const float* __restrict__ qkv, const float* __restrict__ ascale,
    const float* __restrict__ dshift, const float* __restrict__ cl,
    const float* __restrict__ wl, const float* __restrict__ bl,
    float* __restrict__ out) {
    __shared__ float sv[86 * SVW];     // padded BN'd v image (halo 11, zeros outside)
    __shared__ float sw[16 * 529];     // all 16 filters
    __shared__ float sck[16];          // cl[b,k,vc] + b_lconv[k]
    __shared__ float saq[64], sdq[64];

    int vc = blockIdx.x, b = blockIdx.y;
    int tid = threadIdx.x;

    for (int i = tid; i < 16 * 529; i += 256) sw[i] = wl[i];
    if (tid < 64) { saq[tid] = ascale[tid]; sdq[tid] = dshift[tid]; }
    if (tid < 16) sck[tid] = cl[((size_t)b * 16 + tid) * 64 + vc] + bl[tid];

    float av = ascale[64 + vc], dv = dshift[64 + vc];
    const float* vrow = qkv + ((size_t)b * COUT + 80 + vc) * MPIX;
    for (int i = tid; i < 86 * 86; i += 256) {
        int yy = i / 86, xx = i - yy * 86;
        int iy = yy - PADH, ix = xx - PADH;
        float val = 0.f;
        if ((unsigned)iy < 64u && (unsigned)ix < 64u)
            val = fmaf(av, vrow[iy * 64 + ix], dv);
        sv[yy * SVW + xx] = val;
    }
    __syncthreads();

    const float* qb = qkv + (size_t)b * COUT * MPIX;
    float* ob = out + (size_t)b * 256 * MPIX;
    int x = tid & 63;

    for (int pass = 0; pass < 2; pass++) {
        int mbase = pass * 2048;
        int y0 = (mbase + tid) >> 6;  // row of pixel j=0; j adds 4 rows
        int bj[8];
#pragma unroll
        for (int j = 0; j < 8; j++) bj[j] = (y0 + j * 4) * SVW + x;

        float acc[16][8];
#pragma unroll
        for (int k = 0; k < 16; k++)
#pragma unroll
            for (int j = 0; j < 8; j++) acc[k][j] = 0.f;

#pragma unroll 1
        for (int dy = 0; dy < 23; dy++) {
            int rowoff = dy * SVW;
#pragma unroll 1
            for (int dx = 0; dx < 23; dx++) {
                int off = rowoff + dx;
                float vv[8];
#pragma unroll
                for (int j = 0; j < 8; j++) vv[j] = sv[bj[j] + off];
                const float* wp = &sw[dy * 23 + dx];
#pragma unroll
                for (int k = 0; k < 16; k++) {
                    float wv = wp[k * 529];
#pragma unroll
                    for (int j = 0; j < 8; j++) acc[k][j] = fmaf(wv, vv[j], acc[k][j]);
                }
            }
        }

        // epilogue: out[b, n*64+vc, m] = sum_k q_bn[k*4+n, m] * (cl[k]+bias[k]+pl[k, m])
#pragma unroll 1
        for (int j = 0; j < 8; j++) {
            int m = mbase + j * 256 + tid;
            float o0 = 0.f, o1 = 0.f, o2 = 0.f, o3 = 0.f;
#pragma unroll
            for (int k = 0; k < 16; k++) {
                float lam = sck[k] + acc[k][j];
                int c = k * 4;
                float q0 = fmaf(saq[c + 0], qb[(size_t)(c + 0) * MPIX + m], sdq[c + 0]);
                float q1 = fmaf(saq[c + 1], qb[(size_t)(c + 1) * MPIX + m], sdq[c + 1]);
                float q2 = fmaf(saq[c + 2], qb[(size_t)(c + 2) * MPIX + m], sdq[c + 2]);
                float q3 = fmaf(saq[c + 3], qb[(size_t)(c + 3) * MPIX + m], sdq[c + 3]);
                o0 = fmaf(q0, lam, o0);
                o1 = fmaf(q1, lam, o1);
                o2 = fmaf(q2, lam, o2);
                o3 = fmaf(q3, lam, o3);
            }
            ob[(size_t)(0 * 64 + vc) * MPIX + m] = o0;
            ob[(size_t)(1 * 64 + vc) * MPIX + m] = o1;
            ob[(size_t)(2 * 64 + vc) * MPIX + m] = o2;
            ob[(size_t)(3 * 64 + vc) * MPIX + m] = o3;
        }
    }
}

// ---------------- launch ----------------
extern "C" void kernel_launch(void* const* d_in, const int* in_sizes, int n_in,
                              void* d_out, int out_size, void* d_ws, size_t ws_size,
                              hipStream_t stream) {
    const float* x      = (const float*)d_in[0];
    const float* w_qkv  = (const float*)d_in[1];
    const float* gq     = (const float*)d_in[2];
    const float* bq     = (const float*)d_in[3];
    const float* gv     = (const float*)d_in[4];
    const float* bv     = (const float*)d_in[5];
    const float* wl     = (const float*)d_in[6];
    const float* bl     = (const float*)d_in[7];
    float* out = (float*)d_out;

    float* ws     = (float*)d_ws;
    float* qkv    = ws;                    // 16*144*4096 = 9,437,184
    float* p      = qkv + 9437184;         // 16*16*4096  = 1,048,576
    float* part   = p + 1048576;           // 128*16*2    = 4,096
    float* ascale = part + 4096;           // 128
    float* dshift = ascale + 128;          // 128
    float* clpart = dshift + 128;          // 16*16*16*64 = 262,144
    float* clb    = clpart + 262144;       // 16*16*64    = 16,384
    // total ws use: 10,768,640 floats = 43.1 MB

    gemm_qkv<<<dim3(16, 3, 16), 256, 0, stream>>>(x, w_qkv, qkv);
    stats_partial<<<dim3(128, 16), 256, 0, stream>>>(qkv, part);
    stats_finalize<<<1, 128, 0, stream>>>(part, gq, bq, gv, bv, ascale, dshift);
    softmax_k<<<256, 256, 0, stream>>>(qkv, p);
    cl_partial<<<dim3(16, 16), 256, 0, stream>>>(qkv, p, ascale, dshift, clpart);
    cl_reduce<<<16, 256, 0, stream>>>(clpart, clb);
    lambda_main<<<dim3(64, 16), 256, 0, stream>>>(qkv, ascale, dshift, clb, wl, bl, out);
}